// Round 3
// baseline (1064.209 us; speedup 1.0000x reference)
//
#include <hip/hip_runtime.h>

typedef __attribute__((ext_vector_type(8))) short bf16x8;
typedef __attribute__((ext_vector_type(4))) float f32x4;

#define XSTRIDE 40    // X row stride in shorts (32 data + 8 pad = 80B, 16B aligned)
#define WROW    264   // weight-chunk row stride in shorts (528B, 16B aligned)
#define MSTRIDE 264   // mat16 row stride in shorts (528B, 16B aligned)

__device__ __forceinline__ float b2f(unsigned short u) {
    union { unsigned int i; float f; } v; v.i = ((unsigned int)u) << 16; return v.f;
}
__device__ __forceinline__ unsigned short f2b(float f) {
    union { float f; unsigned int i; } v; v.f = f;
    unsigned int x = v.i;
    return (unsigned short)((x + 0x7fffu + ((x >> 16) & 1u)) >> 16);  // RNE
}

template<bool F32>
__device__ __forceinline__ float ldf(const void* p, int i) {
    if constexpr (F32) return ((const float*)p)[i];
    else               return b2f(((const unsigned short*)p)[i]);
}

// load 8 consecutive elements at element-index idx (multiple of 8), store as 8 bf16 to LDS
template<bool F32>
__device__ __forceinline__ void ld8(const void* src, size_t idx, unsigned short* dst) {
    if constexpr (F32) {
        const float* s = (const float*)src + idx;
        const float4 a = *(const float4*)s;
        const float4 b = *(const float4*)(s + 4);
        unsigned short t[8];
        t[0] = f2b(a.x); t[1] = f2b(a.y); t[2] = f2b(a.z); t[3] = f2b(a.w);
        t[4] = f2b(b.x); t[5] = f2b(b.y); t[6] = f2b(b.z); t[7] = f2b(b.w);
        *(uint4*)dst = *(const uint4*)t;
    } else {
        *(uint4*)dst = *(const uint4*)((const unsigned short*)src + idx);
    }
}

// Fully fused temporal attention: one WG = 2 batch elements, 4 waves.
// Wave w owns heads {2w, 2w+1} (cols [64w, 64w+64) of the K-half / V-half).
// Templated on input/output dtype; on-device dtype sniff picks the live variant.
template<bool F32>
__global__ __launch_bounds__(256, 2) void ta_fused(
    const void* __restrict__ node,
    const void* __restrict__ timef,
    const void* __restrict__ edge,
    const void* __restrict__ nbrnode,
    const void* __restrict__ nbrtime,
    const int* __restrict__ nmask,
    const void* __restrict__ WQ,     // [256 k][256 n] native
    const void* __restrict__ WKV,    // [384 k][512 n] native
    const void* __restrict__ WO,     // [256 k][256 n] native
    const void* __restrict__ bO,
    const void* __restrict__ gam,
    const void* __restrict__ bet,
    void* __restrict__ out)
{
    // ---- dtype sniff (block-uniform): bf16 N(0,1) data has exponent-field in
    // [110,135] at ~100% of even ushort slots; f32 data puts uniform mantissa
    // bits there (~10% in range). ----
    {
        const unsigned short* sn = (const unsigned short*)node;
        int c = 0;
        for (int i = 0; i < 64; i++) {
            const int e = (sn[2 * i] >> 7) & 0xFF;
            c += (e >= 110 && e <= 135) ? 1 : 0;
        }
        const bool isBf16 = (c >= 40);
        if (isBf16 == F32) return;     // wrong variant for the actual data
    }

    __shared__ __align__(16) unsigned short Wst[32 * WROW];     // weight k-chunk, [k][n^swz]
    __shared__ __align__(16) unsigned short Xst[64 * XSTRIDE];  // X k-chunk [m][k]
    __shared__ __align__(16) unsigned short Rb[16 * MSTRIDE];   // residual R, padded to M=16
    __shared__ __align__(16) unsigned short Ob[16 * MSTRIDE];   // attention out O, padded to M=16
    __shared__ float Qs[2][256];
    __shared__ float lnb[2][256];
    __shared__ int   mk[2][32];

    const int gb0  = blockIdx.x * 2;
    const int tid  = threadIdx.x;
    const int w    = tid >> 6;
    const int lane = tid & 63;
    const int l15  = lane & 15;
    const int quad = lane >> 4;

    // mask stride sniff: int64 masks read as int32 have all odd words == 0
    bool m64 = true;
    for (int i = 1; i < 64; i += 2) m64 = m64 && (nmask[i] == 0);

    // ---- init: zero Ob fully, zero Rb rows 2..15 (rows 0,1 loaded below) ----
    {
        unsigned int* pO = (unsigned int*)Ob;
        for (int i = tid; i < 16 * MSTRIDE / 2; i += 256) pO[i] = 0u;
        unsigned int* pR = (unsigned int*)Rb;
        for (int i = tid + MSTRIDE; i < 16 * MSTRIDE / 2; i += 256) pR[i] = 0u;
    }
    if (tid < 64) {               // R rows: concat(node, time) for b=0,1
        const int b = tid >> 5, s = tid & 31;
        if (s < 16) ld8<F32>(node,  (size_t)(gb0 + b) * 128 + s * 8,        &Rb[b * MSTRIDE + s * 8]);
        else        ld8<F32>(timef, (size_t)(gb0 + b) * 128 + (s - 16) * 8, &Rb[b * MSTRIDE + s * 8]);
    } else if (tid < 128) {       // neighbor masks
        const int t = tid - 64, b = t >> 5, n = t & 31;
        const size_t j = (size_t)(gb0 + b) * 32 + n;
        mk[b][n] = m64 ? nmask[2 * j] : nmask[j];
    }
    __syncthreads();

    // stage weight chunk: Wst[k][n ^ swz(k)] = W[kc*32+k][colBase+n], n = 0..255
    // swz(k) = ((k>>3)&3)<<4 makes the strided B-gather conflict-free.
    auto stageW = [&](const void* W, int ldN, int colBase, int kc) {
        const int k = tid >> 3, seg = tid & 7;
        const int g = ((k >> 3) & 3) << 4;
        const size_t srow = (size_t)(kc * 32 + k) * ldN + colBase;
        unsigned short* drow = &Wst[k * WROW];
#pragma unroll
        for (int i = 0; i < 4; i++) {
            const int c = seg * 32 + i * 8;
            ld8<F32>(W, srow + c, drow + (c ^ g));
        }
    };
    auto stageX = [&](int kc) {   // gather concat(nbr_node, edge, nbr_time) k-chunk
        const void* base; int koff;
        if (kc < 4)      { base = nbrnode; koff = kc * 32; }
        else if (kc < 8) { base = edge;    koff = (kc - 4) * 32; }
        else             { base = nbrtime; koff = (kc - 8) * 32; }
        const int r = tid >> 2, s4 = tid & 3;      // r = local row 0..63 (= b*32+n)
        ld8<F32>(base, (size_t)(gb0 * 32 + r) * 128 + koff + s4 * 8, &Xst[r * XSTRIDE + s4 * 8]);
    };
    // B-fragment: n = w*64 + ct*16 + l15 (fixed per lane), k = quad*8 + j.
    // swizzle group for rows quad*8+j (j<8) is exactly `quad`.
    auto loadB = [&](int ct) -> bf16x8 {
        const unsigned short* p =
            &Wst[(quad * 8) * WROW + ((w * 64 + ct * 16 + l15) ^ (quad << 4))];
        bf16x8 f;
#pragma unroll
        for (int j = 0; j < 8; j++) f[j] = (short)p[j * WROW];
        return f;
    };

    const f32x4 zero4 = {0.0f, 0.0f, 0.0f, 0.0f};

    // ================= Phase 0: Q = R @ W_Q  (M=16 padded, rows 0,1 real) =================
    f32x4 accq[4];
#pragma unroll
    for (int ct = 0; ct < 4; ct++) accq[ct] = zero4;
    for (int kc = 0; kc < 8; kc++) {
        __syncthreads();
        stageW(WQ, 256, 0, kc);
        __syncthreads();
        bf16x8 afr = *(const bf16x8*)(&Rb[l15 * MSTRIDE + kc * 32 + quad * 8]);
#pragma unroll
        for (int ct = 0; ct < 4; ct++)
            accq[ct] = __builtin_amdgcn_mfma_f32_16x16x32_bf16(afr, loadB(ct), accq[ct], 0, 0, 0);
    }
    if (quad == 0) {  // C-layout: row = quad*4+reg, col = lane&15; rows 0,1 = batch
#pragma unroll
        for (int ct = 0; ct < 4; ct++) {
            Qs[0][w * 64 + ct * 16 + l15] = accq[ct][0];
            Qs[1][w * 64 + ct * 16 + l15] = accq[ct][1];
        }
    }
    __syncthreads();

    // ================= Phase 1: K = X @ W_KV[:, :256]  (64 x 256, K=384) =================
    f32x4 acc[4][4];
#pragma unroll
    for (int rt = 0; rt < 4; rt++)
#pragma unroll
        for (int ct = 0; ct < 4; ct++) acc[rt][ct] = zero4;
    for (int kc = 0; kc < 12; kc++) {
        __syncthreads();
        stageW(WKV, 512, 0, kc);
        stageX(kc);
        __syncthreads();
        bf16x8 af[4], bfv[4];
#pragma unroll
        for (int rt = 0; rt < 4; rt++)
            af[rt] = *(const bf16x8*)(&Xst[(rt * 16 + l15) * XSTRIDE + quad * 8]);
#pragma unroll
        for (int ct = 0; ct < 4; ct++) bfv[ct] = loadB(ct);
#pragma unroll
        for (int rt = 0; rt < 4; rt++)
#pragma unroll
            for (int ct = 0; ct < 4; ct++)
                acc[rt][ct] = __builtin_amdgcn_mfma_f32_16x16x32_bf16(af[rt], bfv[ct], acc[rt][ct], 0, 0, 0);
    }

    // ================= Phase 2: scores + masked softmax (all in C-layout) =================
    // K acc: lane holds K[row n = rt*16+quad*4+rg][dcol = 64w+ct*16+l15].
    float aw[2][2][2][4];
    const float scl = 0.17677669529663687f;   // 32^-0.5
#pragma unroll
    for (int bb = 0; bb < 2; bb++) {
        float qv[4];
#pragma unroll
        for (int ct = 0; ct < 4; ct++) qv[ct] = Qs[bb][w * 64 + ct * 16 + l15];
#pragma unroll
        for (int hl = 0; hl < 2; hl++) {
            float sv[2][4];
#pragma unroll
            for (int rtl = 0; rtl < 2; rtl++) {
                const int rt = bb * 2 + rtl;
#pragma unroll
                for (int rg = 0; rg < 4; rg++)
                    sv[rtl][rg] = acc[rt][2 * hl][rg] * qv[2 * hl]
                                + acc[rt][2 * hl + 1][rg] * qv[2 * hl + 1];
            }
#pragma unroll
            for (int m = 1; m <= 8; m <<= 1)
#pragma unroll
                for (int rtl = 0; rtl < 2; rtl++)
#pragma unroll
                    for (int rg = 0; rg < 4; rg++)
                        sv[rtl][rg] += __shfl_xor(sv[rtl][rg], m, 64);
            float mx = -3.0e38f;
#pragma unroll
            for (int rtl = 0; rtl < 2; rtl++)
#pragma unroll
                for (int rg = 0; rg < 4; rg++) {
                    const int n = rtl * 16 + quad * 4 + rg;
                    sv[rtl][rg] = (mk[bb][n] != 0) ? sv[rtl][rg] * scl : -1.0e10f;
                    mx = fmaxf(mx, sv[rtl][rg]);
                }
            mx = fmaxf(mx, __shfl_xor(mx, 16, 64));
            mx = fmaxf(mx, __shfl_xor(mx, 32, 64));
            float sum = 0.0f;
#pragma unroll
            for (int rtl = 0; rtl < 2; rtl++)
#pragma unroll
                for (int rg = 0; rg < 4; rg++) {
                    const float e = __expf(sv[rtl][rg] - mx);
                    aw[bb][hl][rtl][rg] = e;
                    sum += e;
                }
            sum += __shfl_xor(sum, 16, 64);
            sum += __shfl_xor(sum, 32, 64);
            const float inv = 1.0f / sum;
#pragma unroll
            for (int rtl = 0; rtl < 2; rtl++)
#pragma unroll
                for (int rg = 0; rg < 4; rg++)
                    aw[bb][hl][rtl][rg] *= inv;
        }
    }

    // ================= Phase 3: V = X @ W_KV[:, 256:]  =================
#pragma unroll
    for (int rt = 0; rt < 4; rt++)
#pragma unroll
        for (int ct = 0; ct < 4; ct++) acc[rt][ct] = zero4;
    for (int kc = 0; kc < 12; kc++) {
        __syncthreads();
        stageW(WKV, 512, 256, kc);
        stageX(kc);
        __syncthreads();
        bf16x8 af[4], bfv[4];
#pragma unroll
        for (int rt = 0; rt < 4; rt++)
            af[rt] = *(const bf16x8*)(&Xst[(rt * 16 + l15) * XSTRIDE + quad * 8]);
#pragma unroll
        for (int ct = 0; ct < 4; ct++) bfv[ct] = loadB(ct);
#pragma unroll
        for (int rt = 0; rt < 4; rt++)
#pragma unroll
            for (int ct = 0; ct < 4; ct++)
                acc[rt][ct] = __builtin_amdgcn_mfma_f32_16x16x32_bf16(af[rt], bfv[ct], acc[rt][ct], 0, 0, 0);
    }

    // ================= Phase 4: O = A @ V  (reduce over rows n -> quad shuffles) =========
#pragma unroll
    for (int bb = 0; bb < 2; bb++)
#pragma unroll
        for (int hl = 0; hl < 2; hl++)
#pragma unroll
            for (int ctl = 0; ctl < 2; ctl++) {
                const int ct = hl * 2 + ctl;
                float o = 0.0f;
#pragma unroll
                for (int rtl = 0; rtl < 2; rtl++)
#pragma unroll
                    for (int rg = 0; rg < 4; rg++)
                        o += aw[bb][hl][rtl][rg] * acc[bb * 2 + rtl][ct][rg];
                o += __shfl_xor(o, 16, 64);
                o += __shfl_xor(o, 32, 64);
                if (quad == 0) {
                    const int col = (w * 2 + hl) * 32 + ctl * 16 + l15;
                    Ob[bb * MSTRIDE + col] = f2b(o);
                }
            }
    __syncthreads();

    // ================= Phase 5: out = O @ W_O + b_O + R, then LayerNorm =================
    f32x4 acco[4];
#pragma unroll
    for (int ct = 0; ct < 4; ct++) acco[ct] = zero4;
    for (int kc = 0; kc < 8; kc++) {
        __syncthreads();
        stageW(WO, 256, 0, kc);
        __syncthreads();
        bf16x8 afr = *(const bf16x8*)(&Ob[l15 * MSTRIDE + kc * 32 + quad * 8]);
#pragma unroll
        for (int ct = 0; ct < 4; ct++)
            acco[ct] = __builtin_amdgcn_mfma_f32_16x16x32_bf16(afr, loadB(ct), acco[ct], 0, 0, 0);
    }
    if (quad == 0) {
#pragma unroll
        for (int ct = 0; ct < 4; ct++) {
#pragma unroll
            for (int r = 0; r < 2; r++) {
                const int col = w * 64 + ct * 16 + l15;
                lnb[r][col] = acco[ct][r] + ldf<F32>(bO, col) + b2f(Rb[r * MSTRIDE + col]);
            }
        }
    }
    __syncthreads();

    if (w < 2) {   // wave 0 -> batch 0, wave 1 -> batch 1
        const int bb = w;
        float x[4]; float s = 0.0f;
#pragma unroll
        for (int i = 0; i < 4; i++) { x[i] = lnb[bb][lane + i * 64]; s += x[i]; }
#pragma unroll
        for (int m = 1; m <= 32; m <<= 1) s += __shfl_xor(s, m, 64);
        const float mu = s * (1.0f / 256.0f);
        float s2 = 0.0f;
#pragma unroll
        for (int i = 0; i < 4; i++) { const float d = x[i] - mu; s2 += d * d; }
#pragma unroll
        for (int m = 1; m <= 32; m <<= 1) s2 += __shfl_xor(s2, m, 64);
        const float rstd = rsqrtf(s2 * (1.0f / 256.0f) + 1e-5f);
#pragma unroll
        for (int i = 0; i < 4; i++) {
            const int col = lane + i * 64;
            const float y = (x[i] - mu) * rstd * ldf<F32>(gam, col) + ldf<F32>(bet, col);
            if constexpr (F32) ((float*)out)[(size_t)(gb0 + bb) * 256 + col] = y;
            else ((unsigned short*)out)[(size_t)(gb0 + bb) * 256 + col] = f2b(y);
        }
    }
}

extern "C" void kernel_launch(void* const* d_in, const int* in_sizes, int n_in,
                              void* d_out, int out_size, void* d_ws, size_t ws_size,
                              hipStream_t stream) {
    const void* node    = d_in[0];
    const void* timef   = d_in[1];
    const void* edge    = d_in[2];
    const void* nbrnode = d_in[3];
    const void* nbrtime = d_in[4];
    const int*  nmask   = (const int*)d_in[5];
    const void* W_Q     = d_in[6];
    const void* W_KV    = d_in[7];
    const void* W_O     = d_in[8];
    const void* bO      = d_in[9];
    const void* gam     = d_in[10];
    const void* bet     = d_in[11];

    // Launch both dtype variants; the on-device sniff makes exactly one do work.
    ta_fused<false><<<4096, 256, 0, stream>>>(node, timef, edge, nbrnode, nbrtime, nmask,
                                              W_Q, W_KV, W_O, bO, gam, bet, d_out);
    ta_fused<true><<<4096, 256, 0, stream>>>(node, timef, edge, nbrnode, nbrtime, nmask,
                                             W_Q, W_KV, W_O, bO, gam, bet, d_out);
}

// Round 4
// 755.918 us; speedup vs baseline: 1.4078x; 1.4078x over previous
//
#include <hip/hip_runtime.h>

typedef __attribute__((ext_vector_type(8))) short bf16x8;
typedef __attribute__((ext_vector_type(4))) float f32x4;

#define WST     40    // Wst/Xst row stride in shorts (64B data + 16B pad, 16B aligned)
#define MSTRIDE 264   // mat16 row stride in shorts (528B, 16B aligned)

// Pre-converted transposed weights (bf16, [n][k]) — module-scope device memory,
// rewritten every call by transcvt, so no d_ws / ws_size dependency.
__device__ __align__(16) unsigned short g_WQT[256 * 256];
__device__ __align__(16) unsigned short g_WKVT[512 * 384];
__device__ __align__(16) unsigned short g_WOT[256 * 256];

__device__ __forceinline__ float b2f(unsigned short u) {
    union { unsigned int i; float f; } v; v.i = ((unsigned int)u) << 16; return v.f;
}
__device__ __forceinline__ unsigned short f2b(float f) {
    union { float f; unsigned int i; } v; v.f = f;
    unsigned int x = v.i;
    return (unsigned short)((x + 0x7fffu + ((x >> 16) & 1u)) >> 16);  // RNE
}

// dst[c][r] = bf16(src[r][c]) — f32 [R][C] -> bf16 [C][R]; dims multiples of 32.
__global__ void transcvt(const float* __restrict__ src, unsigned short* __restrict__ dst,
                         int R, int C) {
    __shared__ float tile[32][33];
    const int c0 = blockIdx.x * 32, r0 = blockIdx.y * 32;
    const int tx = threadIdx.x, ty = threadIdx.y;   // 32 x 8
#pragma unroll
    for (int i = 0; i < 32; i += 8)
        tile[ty + i][tx] = src[(size_t)(r0 + ty + i) * C + (c0 + tx)];
    __syncthreads();
#pragma unroll
    for (int i = 0; i < 32; i += 8)
        dst[(size_t)(c0 + ty + i) * R + (r0 + tx)] = f2b(tile[tx][ty + i]);
}

// load 8 consecutive f32, convert, store 8 bf16 (16B) to LDS
__device__ __forceinline__ void ld8f(const float* __restrict__ s, unsigned short* dst) {
    const float4 a = *(const float4*)s;
    const float4 b = *(const float4*)(s + 4);
    unsigned short t[8];
    t[0] = f2b(a.x); t[1] = f2b(a.y); t[2] = f2b(a.z); t[3] = f2b(a.w);
    t[4] = f2b(b.x); t[5] = f2b(b.y); t[6] = f2b(b.z); t[7] = f2b(b.w);
    *(uint4*)dst = *(const uint4*)t;
}

// Fully fused temporal attention: one WG = 2 batch elements, 4 waves.
// Wave w owns heads {2w, 2w+1} (cols [64w, 64w+64) of the K-half / V-half).
// K and V projections share one kc loop (same A-fragments, both B-halves staged).
__global__ __launch_bounds__(256, 2) void ta_fused(
    const float* __restrict__ node,
    const float* __restrict__ timef,
    const float* __restrict__ edge,
    const float* __restrict__ nbrnode,
    const float* __restrict__ nbrtime,
    const int* __restrict__ nmask,
    const float* __restrict__ bO,
    const float* __restrict__ gam,
    const float* __restrict__ bet,
    float* __restrict__ out)
{
    __shared__ __align__(16) unsigned short Wst[512 * WST];     // 40 KB weight k-chunk [n][k]
    __shared__ __align__(16) unsigned short Xst[64 * WST];      // 5 KB  X k-chunk [m][k]
    __shared__ __align__(16) unsigned short Rb[16 * MSTRIDE];   // residual R, padded to M=16
    __shared__ __align__(16) unsigned short Ob[16 * MSTRIDE];   // attention out O, padded to M=16
    __shared__ float Qs[2][256];
    __shared__ float lnb[2][256];
    __shared__ int   mk[2][32];

    const int gb0  = blockIdx.x * 2;
    const int tid  = threadIdx.x;
    const int w    = tid >> 6;
    const int lane = tid & 63;
    const int l15  = lane & 15;
    const int quad = lane >> 4;

    // mask stride sniff: int64 masks read as int32 have all odd words == 0
    bool m64 = true;
    for (int i = 1; i < 64; i += 2) m64 = m64 && (nmask[i] == 0);

    // ---- init: zero Ob fully, zero Rb rows 2..15 (rows 0,1 loaded below) ----
    {
        unsigned int* pO = (unsigned int*)Ob;
        for (int i = tid; i < 16 * MSTRIDE / 2; i += 256) pO[i] = 0u;
        unsigned int* pR = (unsigned int*)Rb;
        for (int i = tid + MSTRIDE; i < 16 * MSTRIDE / 2; i += 256) pR[i] = 0u;
    }
    if (tid < 64) {               // R rows: concat(node, time) for b=0,1
        const int b = tid >> 5, s = tid & 31;
        if (s < 16) ld8f(node  + (size_t)(gb0 + b) * 128 + s * 8,        &Rb[b * MSTRIDE + s * 8]);
        else        ld8f(timef + (size_t)(gb0 + b) * 128 + (s - 16) * 8, &Rb[b * MSTRIDE + s * 8]);
    } else if (tid < 128) {       // neighbor masks
        const int t = tid - 64, b = t >> 5, n = t & 31;
        const size_t j = (size_t)(gb0 + b) * 32 + n;
        mk[b][n] = m64 ? nmask[2 * j] : nmask[j];
    }
    __syncthreads();

    // stage k-chunk of a transposed bf16 weight: Wst[row][0..32) = WT[row][kc*32..+32)
    auto stageWT = [&](const unsigned short* __restrict__ WT, int rows, int Kdim, int kc) {
        for (int r0 = 0; r0 < rows; r0 += 256) {
            const int row = r0 + tid;
            const unsigned short* s = WT + (size_t)row * Kdim + kc * 32;
            unsigned short* d = &Wst[row * WST];
#pragma unroll
            for (int i = 0; i < 4; i++)
                *(uint4*)(d + i * 8) = *(const uint4*)(s + i * 8);
        }
    };
    auto stageX = [&](int kc) {   // gather concat(nbr_node, edge, nbr_time) k-chunk
        const float* base; int koff;
        if (kc < 4)      { base = nbrnode; koff = kc * 32; }
        else if (kc < 8) { base = edge;    koff = (kc - 4) * 32; }
        else             { base = nbrtime; koff = (kc - 8) * 32; }
        const int r = tid >> 2, s4 = tid & 3;      // r = local row 0..63 (= b*32+n)
        ld8f(base + (size_t)(gb0 * 32 + r) * 128 + koff + s4 * 8, &Xst[r * WST + s4 * 8]);
    };
    // B-fragment: n = rowBase + w*64 + ct*16 + l15, k = quad*8 + j  -> one b128
    auto loadB = [&](int rowBase, int ct) -> bf16x8 {
        return *(const bf16x8*)(&Wst[(rowBase + w * 64 + ct * 16 + l15) * WST + quad * 8]);
    };

    const f32x4 zero4 = {0.0f, 0.0f, 0.0f, 0.0f};

    // ================= Phase 0: Q = R @ W_Q  (M=16 padded, rows 0,1 real) =================
    f32x4 accq[4];
#pragma unroll
    for (int ct = 0; ct < 4; ct++) accq[ct] = zero4;
    for (int kc = 0; kc < 8; kc++) {
        __syncthreads();
        stageWT(g_WQT, 256, 256, kc);
        __syncthreads();
        bf16x8 afr = *(const bf16x8*)(&Rb[l15 * MSTRIDE + kc * 32 + quad * 8]);
#pragma unroll
        for (int ct = 0; ct < 4; ct++)
            accq[ct] = __builtin_amdgcn_mfma_f32_16x16x32_bf16(afr, loadB(0, ct), accq[ct], 0, 0, 0);
    }
    if (quad == 0) {  // C-layout: row = quad*4+reg, col = lane&15; rows 0,1 = batch
#pragma unroll
        for (int ct = 0; ct < 4; ct++) {
            Qs[0][w * 64 + ct * 16 + l15] = accq[ct][0];
            Qs[1][w * 64 + ct * 16 + l15] = accq[ct][1];
        }
    }

    // ============ Phase 1: K,V = X @ W_KV  fused (64 x 256 each, K=384) ============
    f32x4 accK[4][4], accV[4][4];
#pragma unroll
    for (int rt = 0; rt < 4; rt++)
#pragma unroll
        for (int ct = 0; ct < 4; ct++) { accK[rt][ct] = zero4; accV[rt][ct] = zero4; }
    for (int kc = 0; kc < 12; kc++) {
        __syncthreads();
        stageWT(g_WKVT, 512, 384, kc);
        stageX(kc);
        __syncthreads();
        bf16x8 af[4];
#pragma unroll
        for (int rt = 0; rt < 4; rt++)
            af[rt] = *(const bf16x8*)(&Xst[(rt * 16 + l15) * WST + quad * 8]);
#pragma unroll
        for (int ct = 0; ct < 4; ct++) {
            const bf16x8 bK = loadB(0, ct);
            const bf16x8 bV = loadB(256, ct);
#pragma unroll
            for (int rt = 0; rt < 4; rt++) {
                accK[rt][ct] = __builtin_amdgcn_mfma_f32_16x16x32_bf16(af[rt], bK, accK[rt][ct], 0, 0, 0);
                accV[rt][ct] = __builtin_amdgcn_mfma_f32_16x16x32_bf16(af[rt], bV, accV[rt][ct], 0, 0, 0);
            }
        }
    }

    // ================= Phase 2: scores + masked softmax (all in C-layout) =================
    // accK: lane holds K[row n = rt*16+quad*4+rg][dcol = 64w+ct*16+l15].
    float aw[2][2][2][4];
    const float scl = 0.17677669529663687f;   // 32^-0.5
#pragma unroll
    for (int bb = 0; bb < 2; bb++) {
        float qv[4];
#pragma unroll
        for (int ct = 0; ct < 4; ct++) qv[ct] = Qs[bb][w * 64 + ct * 16 + l15];
#pragma unroll
        for (int hl = 0; hl < 2; hl++) {
            float sv[2][4];
#pragma unroll
            for (int rtl = 0; rtl < 2; rtl++) {
                const int rt = bb * 2 + rtl;
#pragma unroll
                for (int rg = 0; rg < 4; rg++)
                    sv[rtl][rg] = accK[rt][2 * hl][rg] * qv[2 * hl]
                                + accK[rt][2 * hl + 1][rg] * qv[2 * hl + 1];
            }
#pragma unroll
            for (int m = 1; m <= 8; m <<= 1)
#pragma unroll
                for (int rtl = 0; rtl < 2; rtl++)
#pragma unroll
                    for (int rg = 0; rg < 4; rg++)
                        sv[rtl][rg] += __shfl_xor(sv[rtl][rg], m, 64);
            float mx = -3.0e38f;
#pragma unroll
            for (int rtl = 0; rtl < 2; rtl++)
#pragma unroll
                for (int rg = 0; rg < 4; rg++) {
                    const int n = rtl * 16 + quad * 4 + rg;
                    sv[rtl][rg] = (mk[bb][n] != 0) ? sv[rtl][rg] * scl : -1.0e10f;
                    mx = fmaxf(mx, sv[rtl][rg]);
                }
            mx = fmaxf(mx, __shfl_xor(mx, 16, 64));
            mx = fmaxf(mx, __shfl_xor(mx, 32, 64));
            float sum = 0.0f;
#pragma unroll
            for (int rtl = 0; rtl < 2; rtl++)
#pragma unroll
                for (int rg = 0; rg < 4; rg++) {
                    const float e = __expf(sv[rtl][rg] - mx);
                    aw[bb][hl][rtl][rg] = e;
                    sum += e;
                }
            sum += __shfl_xor(sum, 16, 64);
            sum += __shfl_xor(sum, 32, 64);
            const float inv = 1.0f / sum;
#pragma unroll
            for (int rtl = 0; rtl < 2; rtl++)
#pragma unroll
                for (int rg = 0; rg < 4; rg++)
                    aw[bb][hl][rtl][rg] *= inv;
        }
    }

    // ================= Phase 3: O = A @ V  (reduce over rows n -> quad shuffles) =========
#pragma unroll
    for (int bb = 0; bb < 2; bb++)
#pragma unroll
        for (int hl = 0; hl < 2; hl++)
#pragma unroll
            for (int ctl = 0; ctl < 2; ctl++) {
                const int ct = hl * 2 + ctl;
                float o = 0.0f;
#pragma unroll
                for (int rtl = 0; rtl < 2; rtl++)
#pragma unroll
                    for (int rg = 0; rg < 4; rg++)
                        o += aw[bb][hl][rtl][rg] * accV[bb * 2 + rtl][ct][rg];
                o += __shfl_xor(o, 16, 64);
                o += __shfl_xor(o, 32, 64);
                if (quad == 0) {
                    const int col = (w * 2 + hl) * 32 + ctl * 16 + l15;
                    Ob[bb * MSTRIDE + col] = f2b(o);
                }
            }

    // ================= Phase 4: out = O @ W_O + b_O + R, then LayerNorm =================
    f32x4 acco[4];
#pragma unroll
    for (int ct = 0; ct < 4; ct++) acco[ct] = zero4;
    for (int kc = 0; kc < 8; kc++) {
        __syncthreads();   // also covers Ob writes above (and Wst reuse)
        stageWT(g_WOT, 256, 256, kc);
        __syncthreads();
        bf16x8 afr = *(const bf16x8*)(&Ob[l15 * MSTRIDE + kc * 32 + quad * 8]);
#pragma unroll
        for (int ct = 0; ct < 4; ct++)
            acco[ct] = __builtin_amdgcn_mfma_f32_16x16x32_bf16(afr, loadB(0, ct), acco[ct], 0, 0, 0);
    }
    if (quad == 0) {
#pragma unroll
        for (int ct = 0; ct < 4; ct++) {
#pragma unroll
            for (int r = 0; r < 2; r++) {
                const int col = w * 64 + ct * 16 + l15;
                lnb[r][col] = acco[ct][r] + bO[col] + b2f(Rb[r * MSTRIDE + col]);
            }
        }
    }
    __syncthreads();

    if (w < 2) {   // wave 0 -> batch 0, wave 1 -> batch 1
        const int bb = w;
        float x[4]; float s = 0.0f;
#pragma unroll
        for (int i = 0; i < 4; i++) { x[i] = lnb[bb][lane + i * 64]; s += x[i]; }
#pragma unroll
        for (int m = 1; m <= 32; m <<= 1) s += __shfl_xor(s, m, 64);
        const float mu = s * (1.0f / 256.0f);
        float s2 = 0.0f;
#pragma unroll
        for (int i = 0; i < 4; i++) { const float d = x[i] - mu; s2 += d * d; }
#pragma unroll
        for (int m = 1; m <= 32; m <<= 1) s2 += __shfl_xor(s2, m, 64);
        const float rstd = rsqrtf(s2 * (1.0f / 256.0f) + 1e-5f);
#pragma unroll
        for (int i = 0; i < 4; i++) {
            const int col = lane + i * 64;
            out[(size_t)(gb0 + bb) * 256 + col] =
                (x[i] - mu) * rstd * gam[col] + bet[col];
        }
    }
}

extern "C" void kernel_launch(void* const* d_in, const int* in_sizes, int n_in,
                              void* d_out, int out_size, void* d_ws, size_t ws_size,
                              hipStream_t stream) {
    const float* node    = (const float*)d_in[0];
    const float* timef   = (const float*)d_in[1];
    const float* edge    = (const float*)d_in[2];
    const float* nbrnode = (const float*)d_in[3];
    const float* nbrtime = (const float*)d_in[4];
    const int*   nmask   = (const int*)d_in[5];
    const float* W_Q     = (const float*)d_in[6];
    const float* W_KV    = (const float*)d_in[7];
    const float* W_O     = (const float*)d_in[8];
    const float* bO      = (const float*)d_in[9];
    const float* gam     = (const float*)d_in[10];
    const float* bet     = (const float*)d_in[11];

    unsigned short *wqt, *wkvt, *wot;
    hipGetSymbolAddress((void**)&wqt,  HIP_SYMBOL(g_WQT));
    hipGetSymbolAddress((void**)&wkvt, HIP_SYMBOL(g_WKVT));
    hipGetSymbolAddress((void**)&wot,  HIP_SYMBOL(g_WOT));

    transcvt<<<dim3(8, 8),   dim3(32, 8), 0, stream>>>(W_Q,  wqt,  256, 256);
    transcvt<<<dim3(16, 12), dim3(32, 8), 0, stream>>>(W_KV, wkvt, 384, 512);
    transcvt<<<dim3(8, 8),   dim3(32, 8), 0, stream>>>(W_O,  wot,  256, 256);

    ta_fused<<<4096, 256, 0, stream>>>(node, timef, edge, nbrnode, nbrtime, nmask,
                                       bO, gam, bet, (float*)d_out);
}